// Round 10
// baseline (375.777 us; speedup 1.0000x reference)
//
#include <hip/hip_runtime.h>
#include <hip/hip_bf16.h>

// ---------------------------------------------------------------------------
// RGCN link predictor. Atomic-free CSR build + CSR-pull + bf16 MFMA GEMMs.
//   rgcn_conv(x) = x@root + b + sum_r segsum_dst( H_r[src] ) / max(cnt_r[dst],1)
//   Precision plan: layer-1 GEMM does fp32 via bf16 split (Ah*Bh [+Al*Bh]);
//   z1 and z2 are stored bf16 after aggregation (accumulation stays fp32),
//   so layer-2 GEMM is pure-bf16 A (no split) and decoder gathers bf16.
//   CSR: 2-level bucket sort by dst, LDS-local returning atomics only.
// ---------------------------------------------------------------------------

typedef short bf16x8 __attribute__((ext_vector_type(8)));
typedef float f32x4 __attribute__((ext_vector_type(4)));
typedef float f32x2 __attribute__((ext_vector_type(2)));

__device__ __forceinline__ unsigned short f2bf(float f) {
  union { float f; unsigned u; } x; x.f = f;
  unsigned r = x.u + 0x7FFF + ((x.u >> 16) & 1);  // RNE
  return (unsigned short)(r >> 16);
}
__device__ __forceinline__ float bf2f(unsigned short h) {
  union { unsigned u; float f; } x; x.u = ((unsigned)h) << 16;
  return x.f;
}
// unpack a uint holding two bf16 into f32x2 ([0]=low half, [1]=high half)
__device__ __forceinline__ f32x2 bfpair(unsigned u) {
  union { unsigned u; float f; } a, b;
  a.u = u << 16; b.u = u & 0xFFFF0000u;
  f32x2 r; r[0] = a.f; r[1] = b.f; return r;
}
__device__ __forceinline__ unsigned pk2(float a, float b) {
  return (unsigned)f2bf(a) | ((unsigned)f2bf(b) << 16);
}

// ---- level-1 partition: histogram of dst>>9 per block tile ----
__global__ __launch_bounds__(256) void part_hist_kernel(
    const int* __restrict__ ei, int* __restrict__ hist,
    int E, int tile, int NBUCK) {
  __shared__ int lh[256];
  int tid = threadIdx.x;
  lh[tid] = 0;
  __syncthreads();
  int e0 = blockIdx.x * tile;
  int e1 = min(E, e0 + tile);
  for (int e = e0 + tid; e < e1; e += 256) {
    int d = ei[E + e];
    atomicAdd(&lh[d >> 9], 1);
  }
  __syncthreads();
  if (tid < NBUCK) hist[tid * 256 + blockIdx.x] = lh[tid];
}

// scan hist rows (bucket-major) + bucket bases; rewrite hist to global cursors
__global__ __launch_bounds__(256) void part_scan_kernel(
    int* __restrict__ hist, int* __restrict__ bstart, int NBUCK) {
  __shared__ int sA[256], sB[256];
  int t = threadIdx.x;
  int tot = 0;
  if (t < NBUCK) {
    int* row = hist + t * 256;
    for (int i = 0; i < 256; i++) { int v = row[i]; row[i] = tot; tot += v; }
  }
  sA[t] = tot;
  __syncthreads();
  int* src = sA; int* dst = sB;
  for (int off = 1; off < 256; off <<= 1) {
    int v = src[t];
    if (t >= off) v += src[t - off];
    dst[t] = v;
    __syncthreads();
    int* tmp = src; src = dst; dst = tmp;
  }
  int base = src[t] - tot;  // exclusive
  if (t < NBUCK) {
    bstart[t] = base;
    int* row = hist + t * 256;
    for (int i = 0; i < 256; i++) row[i] += base;
    if (t == NBUCK - 1) bstart[NBUCK] = base + tot;
  }
}

// scatter edges into coarse buckets (LDS cursors, plain 4B global stores)
__global__ __launch_bounds__(256) void part_scatter_kernel(
    const int* __restrict__ ei, const int* __restrict__ et,
    const int* __restrict__ hist, unsigned* __restrict__ rec,
    int E, int tile, int NBUCK) {
  __shared__ int ctr[256];
  int tid = threadIdx.x;
  ctr[tid] = (tid < NBUCK) ? hist[tid * 256 + blockIdx.x] : 0;
  __syncthreads();
  int e0 = blockIdx.x * tile;
  int e1 = min(E, e0 + tile);
  for (int e = e0 + tid; e < e1; e += 256) {
    int s = ei[e];
    int d = ei[E + e];
    int t = et[e];
    int p = atomicAdd(&ctr[d >> 9], 1);
    rec[p] = (unsigned)(s | (t << 20) | ((d & 511) << 22));
  }
}

// ---- level-2: one block per bucket (dst window of 512). Produces packed
// sd (start,deg), inv4 and the final dst-grouped eSrcT — LDS atomics only.
__global__ __launch_bounds__(256) void bucket_build_kernel(
    const unsigned* __restrict__ rec, const int* __restrict__ bstart,
    float4* __restrict__ inv4, int2* __restrict__ sd,
    int* __restrict__ eSrcT, int N) {
  __shared__ int c3[1536];
  __shared__ int sA[512], sB[512];
  __shared__ int cur[512];
  int tid = threadIdx.x;
  int dstBase = blockIdx.x << 9;
  int bs = bstart[blockIdx.x], be = bstart[blockIdx.x + 1];
  for (int i = tid; i < 1536; i += 256) c3[i] = 0;
  __syncthreads();
  for (int i = bs + tid; i < be; i += 256) {
    unsigned r = rec[i];
    atomicAdd(&c3[((r >> 20) & 3) * 512 + (r >> 22)], 1);
  }
  __syncthreads();
  for (int i = tid; i < 512; i += 256) {
    int c0 = c3[i], c1 = c3[512 + i], c2 = c3[1024 + i];
    sA[i] = c0 + c1 + c2;
    if (dstBase + i < N) {
      inv4[dstBase + i] = make_float4(1.0f / (float)max(c0, 1),
                                      1.0f / (float)max(c1, 1),
                                      1.0f / (float)max(c2, 1), 0.f);
    }
  }
  __syncthreads();
  int* src = sA; int* dst = sB;
  for (int off = 1; off < 512; off <<= 1) {
    for (int i = tid; i < 512; i += 256) {
      int v = src[i];
      if (i >= off) v += src[i - off];
      dst[i] = v;
    }
    __syncthreads();
    int* tmp = src; src = dst; dst = tmp;
  }
  for (int i = tid; i < 512; i += 256) {
    int excl = (i > 0) ? src[i - 1] : 0;
    int dg = src[i] - excl;
    cur[i] = bs + excl;
    if (dstBase + i < N) sd[dstBase + i] = make_int2(bs + excl, dg);
  }
  __syncthreads();
  for (int i = bs + tid; i < be; i += 256) {
    unsigned r = rec[i];
    int p = atomicAdd(&cur[r >> 22], 1);
    eSrcT[p] = (int)(r & 0x3FFFFF);  // s | t<<20
  }
}

// pack weights into MFMA B-fragment order, split hi/lo. Both layers, one grid.
template <int K, int TN>
__device__ __forceinline__ void pack_one(
    int e, const float* __restrict__ W, const float* __restrict__ root,
    ushort* __restrict__ Bh, ushort* __restrict__ Bl) {
  int slab = e / (K * TN), r = e % (K * TN);
  int k = r / TN, n = r % TN;
  float v = (slab < 3) ? W[(size_t)slab * K * TN + k * TN + n] : root[(size_t)k * TN + n];
  int kc = k >> 5, quad = (k >> 3) & 3, j = k & 7, nt = n >> 4, nn = n & 15;
  int NTt = TN / 16;
  int didx = slab * K * TN + ((kc * NTt + nt) * 64 + quad * 16 + nn) * 8 + j;
  unsigned short h = f2bf(v);
  Bh[didx] = h;
  Bl[didx] = f2bf(v - bf2f(h));
}

__global__ __launch_bounds__(256) void packw2_kernel(
    const float* __restrict__ W1, const float* __restrict__ root1,
    ushort* __restrict__ Bh1, ushort* __restrict__ Bl1,
    const float* __restrict__ W2, const float* __restrict__ root2,
    ushort* __restrict__ Bh2, ushort* __restrict__ Bl2) {
  int e = blockIdx.x * 256 + threadIdx.x;
  if (e < 32768) pack_one<128, 64>(e, W1, root1, Bh1, Bl1);
  else if (e < 32768 + 8192) pack_one<64, 32>(e - 32768, W2, root2, Bh2, Bl2);
}

// Layer-1 split-bf16 MFMA GEMM. Block = 8 waves x 16 rows = 128 rows (halves
// per-row B staging vs 64-row blocks). A fp32 -> hi/lo split in-register.
// H slabs (0-2): Ah*Bh + Al*Bh, output bf16. z slab (3): + Ah*Bl, fp32 + bias.
template <int K, int TN>
__global__ __launch_bounds__(512) void mfma_gemm_kernel(
    const float* __restrict__ A, const ushort* __restrict__ Bh,
    const ushort* __restrict__ Bl, const float* __restrict__ bias,
    ushort* __restrict__ Hb, float* __restrict__ z, int n) {
  constexpr int KC = K / 32;
  constexpr int NTt = TN / 16;
  constexpr int HALF = K * TN / 8;
  __shared__ int4 bsm[2 * HALF];
  const int tid = threadIdx.x;
  const int w = tid >> 6, lane = tid & 63;
  const int quad = lane >> 4, nn = lane & 15;
  const int rowBase = blockIdx.x * 128 + w * 16;

  int row = rowBase + nn;
  if (row >= n) row = n - 1;  // clamp; stores are guarded
  const float* ap = &A[(size_t)row * K + quad * 8];
  bf16x8 ah[KC], al[KC];
#pragma unroll
  for (int kc = 0; kc < KC; kc++) {
    float4 f0 = *(const float4*)(ap + kc * 32);
    float4 f1 = *(const float4*)(ap + kc * 32 + 4);
    float f[8] = {f0.x, f0.y, f0.z, f0.w, f1.x, f1.y, f1.z, f1.w};
#pragma unroll
    for (int j = 0; j < 8; j++) {
      unsigned short h = f2bf(f[j]);
      ah[kc][j] = (short)h;
      al[kc][j] = (short)f2bf(f[j] - bf2f(h));
    }
  }

  const short* bsp = (const short*)bsm;

#pragma unroll 1
  for (int slab = 0; slab < 4; slab++) {
    __syncthreads();
    {
      const int4* gh = (const int4*)(Bh + (size_t)slab * K * TN);
      for (int i = tid; i < HALF; i += 512) bsm[i] = gh[i];
      if (slab == 3) {
        const int4* gl = (const int4*)(Bl + (size_t)slab * K * TN);
        for (int i = tid; i < HALF; i += 512) bsm[HALF + i] = gl[i];
      }
    }
    __syncthreads();

    f32x4 acc[NTt];
#pragma unroll
    for (int j = 0; j < NTt; j++) acc[j] = (f32x4){0.f, 0.f, 0.f, 0.f};

#pragma unroll
    for (int kc = 0; kc < KC; kc++) {
#pragma unroll
      for (int nt = 0; nt < NTt; nt++) {
        bf16x8 b = *(const bf16x8*)&bsp[((kc * NTt + nt) * 64 + lane) * 8];
        acc[nt] = __builtin_amdgcn_mfma_f32_16x16x32_bf16(ah[kc], b, acc[nt], 0, 0, 0);
        acc[nt] = __builtin_amdgcn_mfma_f32_16x16x32_bf16(al[kc], b, acc[nt], 0, 0, 0);
      }
    }
    if (slab == 3) {
#pragma unroll
      for (int kc = 0; kc < KC; kc++) {
#pragma unroll
        for (int nt = 0; nt < NTt; nt++) {
          bf16x8 b = *(const bf16x8*)&bsp[(HALF * 8) + ((kc * NTt + nt) * 64 + lane) * 8];
          acc[nt] = __builtin_amdgcn_mfma_f32_16x16x32_bf16(ah[kc], b, acc[nt], 0, 0, 0);
        }
      }
    }

    // epilogue: D row = quad*4+reg, col = lane&15 (m89-verified)
    int grow0 = rowBase + quad * 4;
#pragma unroll
    for (int nt = 0; nt < NTt; nt++) {
      int col = nt * 16 + nn;
#pragma unroll
      for (int rg = 0; rg < 4; rg++) {
        int grow = grow0 + rg;
        if (grow < n) {
          float v = acc[nt][rg];
          if (slab == 3) z[(size_t)grow * TN + col] = v + bias[col];
          else Hb[((size_t)slab * n + grow) * TN + col] = f2bf(v);
        }
      }
    }
  }
}

// Layer-2 pure-bf16 MFMA GEMM (A = z1b bf16, no split). K=64, TN=32.
// H slabs: 1 MFMA pass, bf16 out. z slab: Ah*Bh + Ah*Bl, fp32 + bias.
__global__ __launch_bounds__(512) void mfma_gemm2_kernel(
    const ushort* __restrict__ Ab, const ushort* __restrict__ Bh,
    const ushort* __restrict__ Bl, const float* __restrict__ bias,
    ushort* __restrict__ Hb, float* __restrict__ z2r, int n) {
  constexpr int KC = 2, NTt = 2, HALF = 64 * 32 / 8;  // 256 int4 = 4 KB
  __shared__ int4 bsm[2 * HALF];
  const int tid = threadIdx.x;
  const int w = tid >> 6, lane = tid & 63;
  const int quad = lane >> 4, nn = lane & 15;
  const int rowBase = blockIdx.x * 128 + w * 16;

  int row = rowBase + nn;
  if (row >= n) row = n - 1;
  const ushort* ap = &Ab[(size_t)row * 64 + quad * 8];
  bf16x8 ah[KC];
  ah[0] = *(const bf16x8*)(ap);
  ah[1] = *(const bf16x8*)(ap + 32);

  const short* bsp = (const short*)bsm;

#pragma unroll 1
  for (int slab = 0; slab < 4; slab++) {
    __syncthreads();
    {
      const int4* gh = (const int4*)(Bh + (size_t)slab * 64 * 32);
      for (int i = tid; i < HALF; i += 512) bsm[i] = gh[i];
      if (slab == 3) {
        const int4* gl = (const int4*)(Bl + (size_t)slab * 64 * 32);
        for (int i = tid; i < HALF; i += 512) bsm[HALF + i] = gl[i];
      }
    }
    __syncthreads();

    f32x4 acc[NTt];
#pragma unroll
    for (int j = 0; j < NTt; j++) acc[j] = (f32x4){0.f, 0.f, 0.f, 0.f};

#pragma unroll
    for (int kc = 0; kc < KC; kc++) {
#pragma unroll
      for (int nt = 0; nt < NTt; nt++) {
        bf16x8 b = *(const bf16x8*)&bsp[((kc * NTt + nt) * 64 + lane) * 8];
        acc[nt] = __builtin_amdgcn_mfma_f32_16x16x32_bf16(ah[kc], b, acc[nt], 0, 0, 0);
      }
    }
    if (slab == 3) {
#pragma unroll
      for (int kc = 0; kc < KC; kc++) {
#pragma unroll
        for (int nt = 0; nt < NTt; nt++) {
          bf16x8 b = *(const bf16x8*)&bsp[(HALF * 8) + ((kc * NTt + nt) * 64 + lane) * 8];
          acc[nt] = __builtin_amdgcn_mfma_f32_16x16x32_bf16(ah[kc], b, acc[nt], 0, 0, 0);
        }
      }
    }

    int grow0 = rowBase + quad * 4;
#pragma unroll
    for (int nt = 0; nt < NTt; nt++) {
      int col = nt * 16 + nn;
#pragma unroll
      for (int rg = 0; rg < 4; rg++) {
        int grow = grow0 + rg;
        if (grow < n) {
          float v = acc[nt][rg];
          if (slab == 3) z2r[(size_t)grow * 32 + col] = v + bias[col];
          else Hb[((size_t)slab * n + grow) * 32 + col] = f2bf(v);
        }
      }
    }
  }
}

// ---- pull, C=64: one wave/node, 8 lanes x 16B/edge, 8 edges in flight.
// Reads fp32 root z1r, accumulates fp32, writes bf16 z1b (ReLU fused).
__global__ __launch_bounds__(256) void pull64_kernel(
    const ushort* __restrict__ Hb, const int* __restrict__ eSrcT,
    const int2* __restrict__ sd, const float4* __restrict__ inv4,
    const float* __restrict__ z1r, ushort* __restrict__ z1b, int N) {
  int w = (blockIdx.x * 256 + threadIdx.x) >> 6;
  if (w >= N) return;
  int lane = threadIdx.x & 63;
  int g = lane >> 3, q = lane & 7;
  int2 s2 = sd[w];
  float4 iv = inv4[w];
  f32x2 acc0 = {0.f, 0.f}, acc1 = acc0, acc2 = acc0, acc3 = acc0;
  for (int i = g; i < s2.y; i += 8) {
    int p = eSrcT[s2.x + i];
    int s = p & 0xFFFFF, t = p >> 20;
    float sc = (t == 0) ? iv.x : ((t == 1) ? iv.y : iv.z);
    f32x2 sc2 = {sc, sc};
    uint4 v = *(const uint4*)&Hb[((size_t)t * N + s) * 64 + q * 8];
    acc0 += bfpair(v.x) * sc2;
    acc1 += bfpair(v.y) * sc2;
    acc2 += bfpair(v.z) * sc2;
    acc3 += bfpair(v.w) * sc2;
  }
  float a[8] = {acc0[0], acc0[1], acc1[0], acc1[1], acc2[0], acc2[1], acc3[0], acc3[1]};
#pragma unroll
  for (int m = 8; m <= 32; m <<= 1)
#pragma unroll
    for (int j = 0; j < 8; j++) a[j] += __shfl_xor(a[j], m);
  if (g == 0) {
    const float4* zr = (const float4*)&z1r[(size_t)w * 64 + q * 8];
    float4 r0 = zr[0], r1 = zr[1];
    float o0 = fmaxf(r0.x + a[0], 0.f), o1 = fmaxf(r0.y + a[1], 0.f);
    float o2 = fmaxf(r0.z + a[2], 0.f), o3 = fmaxf(r0.w + a[3], 0.f);
    float o4 = fmaxf(r1.x + a[4], 0.f), o5 = fmaxf(r1.y + a[5], 0.f);
    float o6 = fmaxf(r1.z + a[6], 0.f), o7 = fmaxf(r1.w + a[7], 0.f);
    uint4 st;
    st.x = pk2(o0, o1); st.y = pk2(o2, o3); st.z = pk2(o4, o5); st.w = pk2(o6, o7);
    *(uint4*)&z1b[(size_t)w * 64 + q * 8] = st;
  }
}

// ---- pull, C=32: 4 lanes x 16B/edge, 16 edges in flight. Root z2r fp32,
// writes bf16 z2b. No ReLU.
__global__ __launch_bounds__(256) void pull32_kernel(
    const ushort* __restrict__ Hb, const int* __restrict__ eSrcT,
    const int2* __restrict__ sd, const float4* __restrict__ inv4,
    const float* __restrict__ z2r, ushort* __restrict__ z2b, int N) {
  int w = (blockIdx.x * 256 + threadIdx.x) >> 6;
  if (w >= N) return;
  int lane = threadIdx.x & 63;
  int g = lane >> 2, q = lane & 3;
  int2 s2 = sd[w];
  float4 iv = inv4[w];
  f32x2 acc0 = {0.f, 0.f}, acc1 = acc0, acc2 = acc0, acc3 = acc0;
  for (int i = g; i < s2.y; i += 16) {
    int p = eSrcT[s2.x + i];
    int s = p & 0xFFFFF, t = p >> 20;
    float sc = (t == 0) ? iv.x : ((t == 1) ? iv.y : iv.z);
    f32x2 sc2 = {sc, sc};
    uint4 v = *(const uint4*)&Hb[((size_t)t * N + s) * 32 + q * 8];
    acc0 += bfpair(v.x) * sc2;
    acc1 += bfpair(v.y) * sc2;
    acc2 += bfpair(v.z) * sc2;
    acc3 += bfpair(v.w) * sc2;
  }
  float a[8] = {acc0[0], acc0[1], acc1[0], acc1[1], acc2[0], acc2[1], acc3[0], acc3[1]};
#pragma unroll
  for (int m = 4; m <= 32; m <<= 1)
#pragma unroll
    for (int j = 0; j < 8; j++) a[j] += __shfl_xor(a[j], m);
  if (g == 0) {
    const float4* zr = (const float4*)&z2r[(size_t)w * 32 + q * 8];
    float4 r0 = zr[0], r1 = zr[1];
    uint4 st;
    st.x = pk2(r0.x + a[0], r0.y + a[1]);
    st.y = pk2(r0.z + a[2], r0.w + a[3]);
    st.z = pk2(r1.x + a[4], r1.y + a[5]);
    st.w = pk2(r1.z + a[6], r1.w + a[7]);
    *(uint4*)&z2b[(size_t)w * 32 + q * 8] = st;
  }
}

// Decoder: one thread per pred edge; z2 gathered as bf16. Wd1 in LDS.
__global__ __launch_bounds__(256) void decoder_kernel(
    const ushort* __restrict__ z2b, const int* __restrict__ pe,
    const float* __restrict__ Wd1, const float* __restrict__ bd1,
    const float* __restrict__ Wd2, const float* __restrict__ bd2,
    float* __restrict__ out, int P) {
  __shared__ float W[64 * 64];
  __shared__ float w2[64], b1s[64];
  int tid = threadIdx.x;
  for (int i = tid * 4; i < 4096; i += 1024) *(float4*)&W[i] = *(const float4*)&Wd1[i];
  if (tid < 64) {
    w2[tid] = Wd2[tid];
    b1s[tid] = bd1[tid];
  }
  __syncthreads();
  int p = blockIdx.x * 256 + tid;
  if (p >= P) return;
  int s = pe[p];
  int d = pe[P + p];
  float zs[32], zd[32];
  const uint4* ps4 = (const uint4*)&z2b[(size_t)s * 32];
  const uint4* pd4 = (const uint4*)&z2b[(size_t)d * 32];
#pragma unroll
  for (int i = 0; i < 4; i++) {
    uint4 u = ps4[i];
    f32x2 p0 = bfpair(u.x), p1 = bfpair(u.y), p2 = bfpair(u.z), p3 = bfpair(u.w);
    zs[8 * i + 0] = p0[0]; zs[8 * i + 1] = p0[1];
    zs[8 * i + 2] = p1[0]; zs[8 * i + 3] = p1[1];
    zs[8 * i + 4] = p2[0]; zs[8 * i + 5] = p2[1];
    zs[8 * i + 6] = p3[0]; zs[8 * i + 7] = p3[1];
    uint4 v = pd4[i];
    f32x2 q0 = bfpair(v.x), q1 = bfpair(v.y), q2 = bfpair(v.z), q3 = bfpair(v.w);
    zd[8 * i + 0] = q0[0]; zd[8 * i + 1] = q0[1];
    zd[8 * i + 2] = q1[0]; zd[8 * i + 3] = q1[1];
    zd[8 * i + 4] = q2[0]; zd[8 * i + 5] = q2[1];
    zd[8 * i + 6] = q3[0]; zd[8 * i + 7] = q3[1];
  }
  float acc = bd2[0];
#pragma unroll 4
  for (int j = 0; j < 64; j++) {
    float h = b1s[j];
#pragma unroll
    for (int i = 0; i < 32; i++) h += zs[i] * W[i * 64 + j];
#pragma unroll
    for (int i = 0; i < 32; i++) h += zd[i] * W[(32 + i) * 64 + j];
    h = fmaxf(h, 0.0f);
    acc += h * w2[j];
  }
  out[p] = acc;
}

extern "C" void kernel_launch(void* const* d_in, const int* in_sizes, int n_in,
                              void* d_out, int out_size, void* d_ws, size_t ws_size,
                              hipStream_t stream) {
  const float* x     = (const float*)d_in[0];
  const int*   ei    = (const int*)d_in[1];
  const int*   et    = (const int*)d_in[2];
  const int*   pe    = (const int*)d_in[3];
  const float* W1    = (const float*)d_in[4];
  const float* root1 = (const float*)d_in[5];
  const float* b1    = (const float*)d_in[6];
  const float* W2    = (const float*)d_in[7];
  const float* root2 = (const float*)d_in[8];
  const float* b2    = (const float*)d_in[9];
  const float* Wd1   = (const float*)d_in[10];
  const float* bd1   = (const float*)d_in[11];
  const float* Wd2   = (const float*)d_in[12];
  const float* bd2   = (const float*)d_in[13];
  float* out = (float*)d_out;

  const int N = in_sizes[0] / 128;  // 100000
  const int E = in_sizes[2];        // 1600000
  const int P = in_sizes[3] / 2;    // 200000

  const int NBUCK = (N + 511) >> 9;         // coarse buckets (dst>>9), <=256
  const int tile  = (E + 255) / 256;        // edges per partition block

  // Workspace layout (float units; N%4==0 so all kN offsets are 16B-aligned):
  //   inv4:0..4N  z1r:4N..68N  z1b(bf16):68N..100N  z2r:100N..132N
  //   z2b(bf16):132N..148N  Hb(bf16):148N..244N  Bpack:244N..245N
  //   ints from 245N: sd 2N | bstart 1K | hist NBUCK*256 | rec E | eSrcT E
  float* ws   = (float*)d_ws;
  float4* inv4 = (float4*)ws;
  float* z1r  = ws + (size_t)4 * N;
  ushort* z1b = (ushort*)(ws + (size_t)68 * N);   // N*64 bf16
  float* z2r  = ws + (size_t)100 * N;             // N*32 fp32
  ushort* z2b = (ushort*)(ws + (size_t)132 * N);  // N*32 bf16
  ushort* Hb  = (ushort*)(ws + (size_t)148 * N);  // 3*N*64 bf16 (L1) / 3*N*32 (L2)
  ushort* Bh1 = (ushort*)(ws + (size_t)244 * N);  // 4*128*64
  ushort* Bl1 = Bh1 + 32768;
  ushort* Bh2 = Bl1 + 32768;                      // 4*64*32
  ushort* Bl2 = Bh2 + 8192;
  int* ib     = (int*)(ws + (size_t)245 * N);
  int2* sd    = (int2*)ib;                        // N int2
  int* bstart = ib + 2 * (size_t)N;               // NBUCK+1 (pad to 1024)
  int* hist   = ib + 2 * (size_t)N + 1024;        // NBUCK*256
  size_t roff = 2 * (size_t)N + 1024 + (size_t)NBUCK * 256;
  roff = (roff + 3) & ~(size_t)3;
  unsigned* rec = (unsigned*)(ib + roff);         // E records (1 uint each)
  int* eSrcT  = ib + roff + (size_t)E;            // E

  // --- CSR build: 2-level bucket sort, LDS atomics only ---
  part_hist_kernel<<<256, 256, 0, stream>>>(ei, hist, E, tile, NBUCK);
  part_scan_kernel<<<1, 256, 0, stream>>>(hist, bstart, NBUCK);
  part_scatter_kernel<<<256, 256, 0, stream>>>(ei, et, hist, rec, E, tile, NBUCK);
  bucket_build_kernel<<<NBUCK, 256, 0, stream>>>(rec, bstart, inv4, sd, eSrcT, N);

  // --- weight packing (both layers, one grid) ---
  packw2_kernel<<<(32768 + 8192 + 255) / 256, 256, 0, stream>>>(
      W1, root1, Bh1, Bl1, W2, root2, Bh2, Bl2);

  const int gb = (N + 127) / 128;  // 1 block = 8 waves = 128 rows
  const int pullBlocks = (N * 64 + 255) / 256;

  // --- layer 1: K=128 -> 64 (fp32 A, split-bf16) ---
  mfma_gemm_kernel<128, 64><<<gb, 512, 0, stream>>>(x, Bh1, Bl1, b1, Hb, z1r, N);
  pull64_kernel<<<pullBlocks, 256, 0, stream>>>(Hb, eSrcT, sd, inv4, z1r, z1b, N);

  // --- layer 2: K=64 -> 32 (bf16 A, no split) ---
  mfma_gemm2_kernel<<<gb, 512, 0, stream>>>(z1b, Bh2, Bl2, b2, Hb, z2r, N);
  pull32_kernel<<<pullBlocks, 256, 0, stream>>>(Hb, eSrcT, sd, inv4, z2r, z2b, N);

  // --- decoder ---
  decoder_kernel<<<(P + 255) / 256, 256, 0, stream>>>(z2b, pe, Wd1, bd1, Wd2, bd2, out, P);
}

// Round 11
// 342.114 us; speedup vs baseline: 1.0984x; 1.0984x over previous
//
#include <hip/hip_runtime.h>
#include <hip/hip_bf16.h>

// ---------------------------------------------------------------------------
// RGCN link predictor. Atomic-free CSR build + CSR-pull + bf16 MFMA GEMMs.
//   rgcn_conv(x) = x@root + b + sum_r segsum_dst( H_r[src] ) / max(cnt_r[dst],1)
//   Precision: layer-1 GEMM fp32 via bf16 split; z1/z2 stored bf16 after fp32
//   accumulation; layer-2 GEMM pure-bf16 A; decoder gathers bf16.
//   CSR build: 2-level bucket sort by dst (256-dst windows), fully parallel
//   scans, LDS-local returning atomics only.
// ---------------------------------------------------------------------------

typedef short bf16x8 __attribute__((ext_vector_type(8)));
typedef float f32x4 __attribute__((ext_vector_type(4)));
typedef float f32x2 __attribute__((ext_vector_type(2)));

__device__ __forceinline__ unsigned short f2bf(float f) {
  union { float f; unsigned u; } x; x.f = f;
  unsigned r = x.u + 0x7FFF + ((x.u >> 16) & 1);  // RNE
  return (unsigned short)(r >> 16);
}
__device__ __forceinline__ float bf2f(unsigned short h) {
  union { unsigned u; float f; } x; x.u = ((unsigned)h) << 16;
  return x.f;
}
__device__ __forceinline__ f32x2 bfpair(unsigned u) {
  union { unsigned u; float f; } a, b;
  a.u = u << 16; b.u = u & 0xFFFF0000u;
  f32x2 r; r[0] = a.f; r[1] = b.f; return r;
}
__device__ __forceinline__ unsigned pk2(float a, float b) {
  return (unsigned)f2bf(a) | ((unsigned)f2bf(b) << 16);
}

// pack weights into MFMA B-fragment order, split hi/lo.
template <int K, int TN>
__device__ __forceinline__ void pack_one(
    int e, const float* __restrict__ W, const float* __restrict__ root,
    ushort* __restrict__ Bh, ushort* __restrict__ Bl) {
  int slab = e / (K * TN), r = e % (K * TN);
  int k = r / TN, n = r % TN;
  float v = (slab < 3) ? W[(size_t)slab * K * TN + k * TN + n] : root[(size_t)k * TN + n];
  int kc = k >> 5, quad = (k >> 3) & 3, j = k & 7, nt = n >> 4, nn = n & 15;
  int NTt = TN / 16;
  int didx = slab * K * TN + ((kc * NTt + nt) * 64 + quad * 16 + nn) * 8 + j;
  unsigned short h = f2bf(v);
  Bh[didx] = h;
  Bl[didx] = f2bf(v - bf2f(h));
}

// ---- blocks 0..255: per-tile histogram of dst>>8. blocks 256..415: packw. ----
__global__ __launch_bounds__(256) void hist_pack_kernel(
    const int* __restrict__ ei, int* __restrict__ hist, int E, int tile, int NBUCK,
    const float* __restrict__ W1, const float* __restrict__ root1,
    ushort* __restrict__ Bh1, ushort* __restrict__ Bl1,
    const float* __restrict__ W2, const float* __restrict__ root2,
    ushort* __restrict__ Bh2, ushort* __restrict__ Bl2) {
  int tid = threadIdx.x;
  if (blockIdx.x >= 256) {
    int e = (blockIdx.x - 256) * 256 + tid;
    if (e < 32768) pack_one<128, 64>(e, W1, root1, Bh1, Bl1);
    else if (e < 32768 + 8192) pack_one<64, 32>(e - 32768, W2, root2, Bh2, Bl2);
    return;
  }
  __shared__ int lh[512];
  for (int i = tid; i < 512; i += 256) lh[i] = 0;
  __syncthreads();
  int e0 = blockIdx.x * tile, e1 = min(E, e0 + tile);
  for (int e = e0 + tid; e < e1; e += 256) atomicAdd(&lh[ei[E + e] >> 8], 1);
  __syncthreads();
  for (int i = tid; i < NBUCK; i += 256) hist[i * 256 + blockIdx.x] = lh[i];
}

// ---- parallel scan of each bucket row (256 entries) -> exclusive, + rowsum ----
__global__ __launch_bounds__(256) void scan_rows_kernel(
    int* __restrict__ hist, int* __restrict__ rowsum) {
  __shared__ int sA[256], sB[256];
  int t = threadIdx.x;
  int* row = hist + blockIdx.x * 256;
  int v = row[t];
  sA[t] = v;
  __syncthreads();
  int* src = sA; int* dst = sB;
  for (int off = 1; off < 256; off <<= 1) {
    int x = src[t];
    if (t >= off) x += src[t - off];
    dst[t] = x;
    __syncthreads();
    int* tmp = src; src = dst; dst = tmp;
  }
  row[t] = src[t] - v;  // exclusive within row
  if (t == 255) rowsum[blockIdx.x] = src[255];
}

// ---- scan of rowsums -> rowbase (= bucket start offsets); rowbase[NBUCK]=E ----
__global__ __launch_bounds__(512) void scan_top_kernel(
    const int* __restrict__ rowsum, int* __restrict__ rowbase, int NBUCK, int E) {
  __shared__ int sA[512], sB[512];
  int t = threadIdx.x;
  int v = (t < NBUCK) ? rowsum[t] : 0;
  sA[t] = v;
  __syncthreads();
  int* src = sA; int* dst = sB;
  for (int off = 1; off < 512; off <<= 1) {
    int x = src[t];
    if (t >= off) x += src[t - off];
    dst[t] = x;
    __syncthreads();
    int* tmp = src; src = dst; dst = tmp;
  }
  if (t < NBUCK) rowbase[t] = src[t] - v;
  if (t == 0) rowbase[NBUCK] = E;
}

// ---- scatter edges into coarse buckets (LDS cursors, plain 4B stores) ----
__global__ __launch_bounds__(256) void part_scatter_kernel(
    const int* __restrict__ ei, const int* __restrict__ et,
    const int* __restrict__ hist, const int* __restrict__ rowbase,
    unsigned* __restrict__ rec, int E, int tile, int NBUCK) {
  __shared__ int ctr[512];
  int tid = threadIdx.x;
  for (int i = tid; i < NBUCK; i += 256)
    ctr[i] = hist[i * 256 + blockIdx.x] + rowbase[i];
  __syncthreads();
  int e0 = blockIdx.x * tile, e1 = min(E, e0 + tile);
  for (int e = e0 + tid; e < e1; e += 256) {
    int s = ei[e];
    int d = ei[E + e];
    int t = et[e];
    int p = atomicAdd(&ctr[d >> 8], 1);
    rec[p] = (unsigned)(s | (t << 20) | ((d & 255) << 22));
  }
}

// ---- one block per 256-dst window: per-(rel,dst) counts, inv4, sd, and the
// final dst-grouped eSrcT — LDS atomics only. ----
__global__ __launch_bounds__(256) void bucket_build_kernel(
    const unsigned* __restrict__ rec, const int* __restrict__ rowbase,
    float4* __restrict__ inv4, int2* __restrict__ sd,
    int* __restrict__ eSrcT, int N) {
  __shared__ int c3[768];
  __shared__ int sA[256], sB[256];
  __shared__ int cur[256];
  int tid = threadIdx.x;
  int dstBase = blockIdx.x << 8;
  int bs = rowbase[blockIdx.x], be = rowbase[blockIdx.x + 1];
  for (int i = tid; i < 768; i += 256) c3[i] = 0;
  __syncthreads();
  for (int i = bs + tid; i < be; i += 256) {
    unsigned r = rec[i];
    atomicAdd(&c3[((r >> 20) & 3) * 256 + (r >> 22)], 1);
  }
  __syncthreads();
  int c0 = c3[tid], c1 = c3[256 + tid], c2 = c3[512 + tid];
  int dgv = c0 + c1 + c2;
  sA[tid] = dgv;
  if (dstBase + tid < N) {
    inv4[dstBase + tid] = make_float4(1.0f / (float)max(c0, 1),
                                      1.0f / (float)max(c1, 1),
                                      1.0f / (float)max(c2, 1), 0.f);
  }
  __syncthreads();
  int* src = sA; int* dst = sB;
  for (int off = 1; off < 256; off <<= 1) {
    int x = src[tid];
    if (tid >= off) x += src[tid - off];
    dst[tid] = x;
    __syncthreads();
    int* tmp = src; src = dst; dst = tmp;
  }
  int excl = src[tid] - dgv;
  cur[tid] = bs + excl;
  if (dstBase + tid < N) sd[dstBase + tid] = make_int2(bs + excl, dgv);
  __syncthreads();
  for (int i = bs + tid; i < be; i += 256) {
    unsigned r = rec[i];
    int p = atomicAdd(&cur[r >> 22], 1);
    eSrcT[p] = (int)(r & 0x3FFFFF);  // s | t<<20
  }
}

// Layer-1 split-bf16 MFMA GEMM. Block = 4 waves x 16 rows = 64 rows (R8-proven
// config). A fp32 -> hi/lo in-register. B staged per-slab in LDS.
// H slabs (0-2): Ah*Bh + Al*Bh, bf16 out. z slab (3): + Ah*Bl, fp32 + bias.
template <int K, int TN>
__global__ __launch_bounds__(256, 4) void mfma_gemm_kernel(
    const float* __restrict__ A, const ushort* __restrict__ Bh,
    const ushort* __restrict__ Bl, const float* __restrict__ bias,
    ushort* __restrict__ Hb, float* __restrict__ z, int n) {
  constexpr int KC = K / 32;
  constexpr int NTt = TN / 16;
  constexpr int HALF = K * TN / 8;
  __shared__ int4 bsm[2 * HALF];
  const int tid = threadIdx.x;
  const int w = tid >> 6, lane = tid & 63;
  const int quad = lane >> 4, nn = lane & 15;
  const int rowBase = blockIdx.x * 64 + w * 16;

  int row = rowBase + nn;
  if (row >= n) row = n - 1;  // clamp; stores are guarded
  const float* ap = &A[(size_t)row * K + quad * 8];
  bf16x8 ah[KC], al[KC];
#pragma unroll
  for (int kc = 0; kc < KC; kc++) {
    float4 f0 = *(const float4*)(ap + kc * 32);
    float4 f1 = *(const float4*)(ap + kc * 32 + 4);
    float f[8] = {f0.x, f0.y, f0.z, f0.w, f1.x, f1.y, f1.z, f1.w};
#pragma unroll
    for (int j = 0; j < 8; j++) {
      unsigned short h = f2bf(f[j]);
      ah[kc][j] = (short)h;
      al[kc][j] = (short)f2bf(f[j] - bf2f(h));
    }
  }

  const short* bsp = (const short*)bsm;

#pragma unroll 1
  for (int slab = 0; slab < 4; slab++) {
    __syncthreads();
    {
      const int4* gh = (const int4*)(Bh + (size_t)slab * K * TN);
      for (int i = tid; i < HALF; i += 256) bsm[i] = gh[i];
      if (slab == 3) {
        const int4* gl = (const int4*)(Bl + (size_t)slab * K * TN);
        for (int i = tid; i < HALF; i += 256) bsm[HALF + i] = gl[i];
      }
    }
    __syncthreads();

    f32x4 acc[NTt];
#pragma unroll
    for (int j = 0; j < NTt; j++) acc[j] = (f32x4){0.f, 0.f, 0.f, 0.f};

#pragma unroll
    for (int kc = 0; kc < KC; kc++) {
#pragma unroll
      for (int nt = 0; nt < NTt; nt++) {
        bf16x8 b = *(const bf16x8*)&bsp[((kc * NTt + nt) * 64 + lane) * 8];
        acc[nt] = __builtin_amdgcn_mfma_f32_16x16x32_bf16(ah[kc], b, acc[nt], 0, 0, 0);
        acc[nt] = __builtin_amdgcn_mfma_f32_16x16x32_bf16(al[kc], b, acc[nt], 0, 0, 0);
      }
    }
    if (slab == 3) {
#pragma unroll
      for (int kc = 0; kc < KC; kc++) {
#pragma unroll
        for (int nt = 0; nt < NTt; nt++) {
          bf16x8 b = *(const bf16x8*)&bsp[(HALF * 8) + ((kc * NTt + nt) * 64 + lane) * 8];
          acc[nt] = __builtin_amdgcn_mfma_f32_16x16x32_bf16(ah[kc], b, acc[nt], 0, 0, 0);
        }
      }
    }

    // epilogue: D row = quad*4+reg, col = lane&15 (m89-verified)
    int grow0 = rowBase + quad * 4;
#pragma unroll
    for (int nt = 0; nt < NTt; nt++) {
      int col = nt * 16 + nn;
#pragma unroll
      for (int rg = 0; rg < 4; rg++) {
        int grow = grow0 + rg;
        if (grow < n) {
          float v = acc[nt][rg];
          if (slab == 3) z[(size_t)grow * TN + col] = v + bias[col];
          else Hb[((size_t)slab * n + grow) * TN + col] = f2bf(v);
        }
      }
    }
  }
}

// Layer-2 pure-bf16 MFMA GEMM (A = z1b bf16, no split). K=64, TN=32.
__global__ __launch_bounds__(256, 4) void mfma_gemm2_kernel(
    const ushort* __restrict__ Ab, const ushort* __restrict__ Bh,
    const ushort* __restrict__ Bl, const float* __restrict__ bias,
    ushort* __restrict__ Hb, float* __restrict__ z2r, int n) {
  constexpr int KC = 2, NTt = 2, HALF = 64 * 32 / 8;  // 256 int4 = 4 KB
  __shared__ int4 bsm[2 * HALF];
  const int tid = threadIdx.x;
  const int w = tid >> 6, lane = tid & 63;
  const int quad = lane >> 4, nn = lane & 15;
  const int rowBase = blockIdx.x * 64 + w * 16;

  int row = rowBase + nn;
  if (row >= n) row = n - 1;
  const ushort* ap = &Ab[(size_t)row * 64 + quad * 8];
  bf16x8 ah[KC];
  ah[0] = *(const bf16x8*)(ap);
  ah[1] = *(const bf16x8*)(ap + 32);

  const short* bsp = (const short*)bsm;

#pragma unroll 1
  for (int slab = 0; slab < 4; slab++) {
    __syncthreads();
    {
      const int4* gh = (const int4*)(Bh + (size_t)slab * 64 * 32);
      for (int i = tid; i < HALF; i += 256) bsm[i] = gh[i];
      if (slab == 3) {
        const int4* gl = (const int4*)(Bl + (size_t)slab * 64 * 32);
        for (int i = tid; i < HALF; i += 256) bsm[HALF + i] = gl[i];
      }
    }
    __syncthreads();

    f32x4 acc[NTt];
#pragma unroll
    for (int j = 0; j < NTt; j++) acc[j] = (f32x4){0.f, 0.f, 0.f, 0.f};

#pragma unroll
    for (int kc = 0; kc < KC; kc++) {
#pragma unroll
      for (int nt = 0; nt < NTt; nt++) {
        bf16x8 b = *(const bf16x8*)&bsp[((kc * NTt + nt) * 64 + lane) * 8];
        acc[nt] = __builtin_amdgcn_mfma_f32_16x16x32_bf16(ah[kc], b, acc[nt], 0, 0, 0);
      }
    }
    if (slab == 3) {
#pragma unroll
      for (int kc = 0; kc < KC; kc++) {
#pragma unroll
        for (int nt = 0; nt < NTt; nt++) {
          bf16x8 b = *(const bf16x8*)&bsp[(HALF * 8) + ((kc * NTt + nt) * 64 + lane) * 8];
          acc[nt] = __builtin_amdgcn_mfma_f32_16x16x32_bf16(ah[kc], b, acc[nt], 0, 0, 0);
        }
      }
    }

    int grow0 = rowBase + quad * 4;
#pragma unroll
    for (int nt = 0; nt < NTt; nt++) {
      int col = nt * 16 + nn;
#pragma unroll
      for (int rg = 0; rg < 4; rg++) {
        int grow = grow0 + rg;
        if (grow < n) {
          float v = acc[nt][rg];
          if (slab == 3) z2r[(size_t)grow * 32 + col] = v + bias[col];
          else Hb[((size_t)slab * n + grow) * 32 + col] = f2bf(v);
        }
      }
    }
  }
}

// ---- pull, C=64: one wave/node, 8 lanes x 16B/edge, 8 edges in flight.
// Reads fp32 root z1r, accumulates fp32, writes bf16 z1b (ReLU fused).
__global__ __launch_bounds__(256) void pull64_kernel(
    const ushort* __restrict__ Hb, const int* __restrict__ eSrcT,
    const int2* __restrict__ sd, const float4* __restrict__ inv4,
    const float* __restrict__ z1r, ushort* __restrict__ z1b, int N) {
  int w = (blockIdx.x * 256 + threadIdx.x) >> 6;
  if (w >= N) return;
  int lane = threadIdx.x & 63;
  int g = lane >> 3, q = lane & 7;
  int2 s2 = sd[w];
  float4 iv = inv4[w];
  f32x2 acc0 = {0.f, 0.f}, acc1 = acc0, acc2 = acc0, acc3 = acc0;
  for (int i = g; i < s2.y; i += 8) {
    int p = eSrcT[s2.x + i];
    int s = p & 0xFFFFF, t = p >> 20;
    float sc = (t == 0) ? iv.x : ((t == 1) ? iv.y : iv.z);
    f32x2 sc2 = {sc, sc};
    uint4 v = *(const uint4*)&Hb[((size_t)t * N + s) * 64 + q * 8];
    acc0 += bfpair(v.x) * sc2;
    acc1 += bfpair(v.y) * sc2;
    acc2 += bfpair(v.z) * sc2;
    acc3 += bfpair(v.w) * sc2;
  }
  float a[8] = {acc0[0], acc0[1], acc1[0], acc1[1], acc2[0], acc2[1], acc3[0], acc3[1]};
#pragma unroll
  for (int m = 8; m <= 32; m <<= 1)
#pragma unroll
    for (int j = 0; j < 8; j++) a[j] += __shfl_xor(a[j], m);
  if (g == 0) {
    const float4* zr = (const float4*)&z1r[(size_t)w * 64 + q * 8];
    float4 r0 = zr[0], r1 = zr[1];
    float o0 = fmaxf(r0.x + a[0], 0.f), o1 = fmaxf(r0.y + a[1], 0.f);
    float o2 = fmaxf(r0.z + a[2], 0.f), o3 = fmaxf(r0.w + a[3], 0.f);
    float o4 = fmaxf(r1.x + a[4], 0.f), o5 = fmaxf(r1.y + a[5], 0.f);
    float o6 = fmaxf(r1.z + a[6], 0.f), o7 = fmaxf(r1.w + a[7], 0.f);
    uint4 st;
    st.x = pk2(o0, o1); st.y = pk2(o2, o3); st.z = pk2(o4, o5); st.w = pk2(o6, o7);
    *(uint4*)&z1b[(size_t)w * 64 + q * 8] = st;
  }
}

// ---- pull, C=32: 4 lanes x 16B/edge, 16 edges in flight. Writes bf16 z2b.
__global__ __launch_bounds__(256) void pull32_kernel(
    const ushort* __restrict__ Hb, const int* __restrict__ eSrcT,
    const int2* __restrict__ sd, const float4* __restrict__ inv4,
    const float* __restrict__ z2r, ushort* __restrict__ z2b, int N) {
  int w = (blockIdx.x * 256 + threadIdx.x) >> 6;
  if (w >= N) return;
  int lane = threadIdx.x & 63;
  int g = lane >> 2, q = lane & 3;
  int2 s2 = sd[w];
  float4 iv = inv4[w];
  f32x2 acc0 = {0.f, 0.f}, acc1 = acc0, acc2 = acc0, acc3 = acc0;
  for (int i = g; i < s2.y; i += 16) {
    int p = eSrcT[s2.x + i];
    int s = p & 0xFFFFF, t = p >> 20;
    float sc = (t == 0) ? iv.x : ((t == 1) ? iv.y : iv.z);
    f32x2 sc2 = {sc, sc};
    uint4 v = *(const uint4*)&Hb[((size_t)t * N + s) * 32 + q * 8];
    acc0 += bfpair(v.x) * sc2;
    acc1 += bfpair(v.y) * sc2;
    acc2 += bfpair(v.z) * sc2;
    acc3 += bfpair(v.w) * sc2;
  }
  float a[8] = {acc0[0], acc0[1], acc1[0], acc1[1], acc2[0], acc2[1], acc3[0], acc3[1]};
#pragma unroll
  for (int m = 4; m <= 32; m <<= 1)
#pragma unroll
    for (int j = 0; j < 8; j++) a[j] += __shfl_xor(a[j], m);
  if (g == 0) {
    const float4* zr = (const float4*)&z2r[(size_t)w * 32 + q * 8];
    float4 r0 = zr[0], r1 = zr[1];
    uint4 st;
    st.x = pk2(r0.x + a[0], r0.y + a[1]);
    st.y = pk2(r0.z + a[2], r0.w + a[3]);
    st.z = pk2(r1.x + a[4], r1.y + a[5]);
    st.w = pk2(r1.z + a[6], r1.w + a[7]);
    *(uint4*)&z2b[(size_t)w * 32 + q * 8] = st;
  }
}

// Decoder: one thread per pred edge; z2 gathered as bf16. Wd1 in LDS.
__global__ __launch_bounds__(256) void decoder_kernel(
    const ushort* __restrict__ z2b, const int* __restrict__ pe,
    const float* __restrict__ Wd1, const float* __restrict__ bd1,
    const float* __restrict__ Wd2, const float* __restrict__ bd2,
    float* __restrict__ out, int P) {
  __shared__ float W[64 * 64];
  __shared__ float w2[64], b1s[64];
  int tid = threadIdx.x;
  for (int i = tid * 4; i < 4096; i += 1024) *(float4*)&W[i] = *(const float4*)&Wd1[i];
  if (tid < 64) {
    w2[tid] = Wd2[tid];
    b1s[tid] = bd1[tid];
  }
  __syncthreads();
  int p = blockIdx.x * 256 + tid;
  if (p >= P) return;
  int s = pe[p];
  int d = pe[P + p];
  float zs[32], zd[32];
  const uint4* ps4 = (const uint4*)&z2b[(size_t)s * 32];
  const uint4* pd4 = (const uint4*)&z2b[(size_t)d * 32];
#pragma unroll
  for (int i = 0; i < 4; i++) {
    uint4 u = ps4[i];
    f32x2 p0 = bfpair(u.x), p1 = bfpair(u.y), p2 = bfpair(u.z), p3 = bfpair(u.w);
    zs[8 * i + 0] = p0[0]; zs[8 * i + 1] = p0[1];
    zs[8 * i + 2] = p1[0]; zs[8 * i + 3] = p1[1];
    zs[8 * i + 4] = p2[0]; zs[8 * i + 5] = p2[1];
    zs[8 * i + 6] = p3[0]; zs[8 * i + 7] = p3[1];
    uint4 v = pd4[i];
    f32x2 q0 = bfpair(v.x), q1 = bfpair(v.y), q2 = bfpair(v.z), q3 = bfpair(v.w);
    zd[8 * i + 0] = q0[0]; zd[8 * i + 1] = q0[1];
    zd[8 * i + 2] = q1[0]; zd[8 * i + 3] = q1[1];
    zd[8 * i + 4] = q2[0]; zd[8 * i + 5] = q2[1];
    zd[8 * i + 6] = q3[0]; zd[8 * i + 7] = q3[1];
  }
  float acc = bd2[0];
#pragma unroll 4
  for (int j = 0; j < 64; j++) {
    float h = b1s[j];
#pragma unroll
    for (int i = 0; i < 32; i++) h += zs[i] * W[i * 64 + j];
#pragma unroll
    for (int i = 0; i < 32; i++) h += zd[i] * W[(32 + i) * 64 + j];
    h = fmaxf(h, 0.0f);
    acc += h * w2[j];
  }
  out[p] = acc;
}

extern "C" void kernel_launch(void* const* d_in, const int* in_sizes, int n_in,
                              void* d_out, int out_size, void* d_ws, size_t ws_size,
                              hipStream_t stream) {
  const float* x     = (const float*)d_in[0];
  const int*   ei    = (const int*)d_in[1];
  const int*   et    = (const int*)d_in[2];
  const int*   pe    = (const int*)d_in[3];
  const float* W1    = (const float*)d_in[4];
  const float* root1 = (const float*)d_in[5];
  const float* b1    = (const float*)d_in[6];
  const float* W2    = (const float*)d_in[7];
  const float* root2 = (const float*)d_in[8];
  const float* b2    = (const float*)d_in[9];
  const float* Wd1   = (const float*)d_in[10];
  const float* bd1   = (const float*)d_in[11];
  const float* Wd2   = (const float*)d_in[12];
  const float* bd2   = (const float*)d_in[13];
  float* out = (float*)d_out;

  const int N = in_sizes[0] / 128;  // 100000
  const int E = in_sizes[2];        // 1600000
  const int P = in_sizes[3] / 2;    // 200000

  const int NBUCK = (N + 255) >> 8;   // 256-dst windows (<=512)
  const int tile  = (E + 255) / 256;  // edges per partition block

  // Workspace layout (float units; N%4==0 so kN offsets are 16B-aligned):
  //   inv4:0..4N  z1r:4N..68N  z1b(bf16):68N..100N  z2r:100N..132N
  //   z2b(bf16):132N..148N  Hb(bf16):148N..244N  Bpack:244N..245N
  //   ints from 245N: sd 2N | rowbase 1K | rowsum 1K | hist NBUCK*256 | rec E | eSrcT E
  float* ws   = (float*)d_ws;
  float4* inv4 = (float4*)ws;
  float* z1r  = ws + (size_t)4 * N;
  ushort* z1b = (ushort*)(ws + (size_t)68 * N);   // N*64 bf16
  float* z2r  = ws + (size_t)100 * N;             // N*32 fp32
  ushort* z2b = (ushort*)(ws + (size_t)132 * N);  // N*32 bf16
  ushort* Hb  = (ushort*)(ws + (size_t)148 * N);  // 3*N*64 bf16 (L1) / 3*N*32 (L2)
  ushort* Bh1 = (ushort*)(ws + (size_t)244 * N);  // 4*128*64
  ushort* Bl1 = Bh1 + 32768;
  ushort* Bh2 = Bl1 + 32768;                      // 4*64*32
  ushort* Bl2 = Bh2 + 8192;
  int* ib      = (int*)(ws + (size_t)245 * N);
  int2* sd     = (int2*)ib;                       // N int2
  int* rowbase = ib + 2 * (size_t)N;              // NBUCK+1 (pad 1024)
  int* rowsum  = rowbase + 1024;                  // NBUCK (pad 1024)
  int* hist    = rowsum + 1024;                   // NBUCK*256
  size_t roff = 2 * (size_t)N + 2048 + (size_t)NBUCK * 256;
  roff = (roff + 3) & ~(size_t)3;
  unsigned* rec = (unsigned*)(ib + roff);         // E records
  int* eSrcT  = ib + roff + (size_t)E;            // E

  // --- CSR build (parallel scans) + weight packing fused into dispatch 1 ---
  hist_pack_kernel<<<256 + 160, 256, 0, stream>>>(
      ei, hist, E, tile, NBUCK, W1, root1, Bh1, Bl1, W2, root2, Bh2, Bl2);
  scan_rows_kernel<<<NBUCK, 256, 0, stream>>>(hist, rowsum);
  scan_top_kernel<<<1, 512, 0, stream>>>(rowsum, rowbase, NBUCK, E);
  part_scatter_kernel<<<256, 256, 0, stream>>>(ei, et, hist, rowbase, rec, E, tile, NBUCK);
  bucket_build_kernel<<<NBUCK, 256, 0, stream>>>(rec, rowbase, inv4, sd, eSrcT, N);

  const int gb = (N + 63) / 64;  // 1 block = 4 waves = 64 rows
  const int pullBlocks = (N * 64 + 255) / 256;

  // --- layer 1: K=128 -> 64 (fp32 A, split-bf16) ---
  mfma_gemm_kernel<128, 64><<<gb, 256, 0, stream>>>(x, Bh1, Bl1, b1, Hb, z1r, N);
  pull64_kernel<<<pullBlocks, 256, 0, stream>>>(Hb, eSrcT, sd, inv4, z1r, z1b, N);

  // --- layer 2: K=64 -> 32 (bf16 A, no split) ---
  mfma_gemm2_kernel<<<gb, 256, 0, stream>>>(z1b, Bh2, Bl2, b2, Hb, z2r, N);
  pull32_kernel<<<pullBlocks, 256, 0, stream>>>(Hb, eSrcT, sd, inv4, z2r, z2b, N);

  // --- decoder ---
  decoder_kernel<<<(P + 255) / 256, 256, 0, stream>>>(z2b, pe, Wd1, bd1, Wd2, bd2, out, P);
}

// Round 13
// 305.540 us; speedup vs baseline: 1.2299x; 1.1197x over previous
//
#include <hip/hip_runtime.h>
#include <hip/hip_bf16.h>

// ---------------------------------------------------------------------------
// RGCN link predictor. Atomic-free CSR build + CSR-pull + bf16 MFMA GEMMs.
//   rgcn_conv(x) = x@root + b + sum_r segsum_dst( H_r[src] ) / max(cnt_r[dst],1)
//   Pulls: channel-exclusive lane groups (no shuffle reduce); per-edge records
//   precomputed as (H-row index, scale) pairs. Decoder runs on MFMA.
//   CSR build: 2-level bucket sort by dst (256-dst windows), parallel scans,
//   LDS-local returning atomics only.
// ---------------------------------------------------------------------------

typedef short bf16x8 __attribute__((ext_vector_type(8)));
typedef float f32x4 __attribute__((ext_vector_type(4)));
typedef float f32x2 __attribute__((ext_vector_type(2)));

__device__ __forceinline__ unsigned short f2bf(float f) {
  union { float f; unsigned u; } x; x.f = f;
  unsigned r = x.u + 0x7FFF + ((x.u >> 16) & 1);  // RNE
  return (unsigned short)(r >> 16);
}
__device__ __forceinline__ float bf2f(unsigned short h) {
  union { unsigned u; float f; } x; x.u = ((unsigned)h) << 16;
  return x.f;
}
__device__ __forceinline__ f32x2 bfpair(unsigned u) {
  union { unsigned u; float f; } a, b;
  a.u = u << 16; b.u = u & 0xFFFF0000u;
  f32x2 r; r[0] = a.f; r[1] = b.f; return r;
}
__device__ __forceinline__ unsigned pk2(float a, float b) {
  return (unsigned)f2bf(a) | ((unsigned)f2bf(b) << 16);
}

// pack weights into MFMA B-fragment order, split hi/lo.
template <int K, int TN>
__device__ __forceinline__ void pack_one(
    int e, const float* __restrict__ W, const float* __restrict__ root,
    ushort* __restrict__ Bh, ushort* __restrict__ Bl) {
  int slab = e / (K * TN), r = e % (K * TN);
  int k = r / TN, n = r % TN;
  float v = (slab < 3) ? W[(size_t)slab * K * TN + k * TN + n] : root[(size_t)k * TN + n];
  int kc = k >> 5, quad = (k >> 3) & 3, j = k & 7, nt = n >> 4, nn = n & 15;
  int NTt = TN / 16;
  int didx = slab * K * TN + ((kc * NTt + nt) * 64 + quad * 16 + nn) * 8 + j;
  unsigned short h = f2bf(v);
  Bh[didx] = h;
  Bl[didx] = f2bf(v - bf2f(h));
}

// blocks 0..255: histogram of dst>>8 per tile. blocks 256..431: weight packing
// (layer1, layer2, decoder Wd1 -> bf16 B-frag order).
__global__ __launch_bounds__(256) void hist_pack_kernel(
    const int* __restrict__ ei, int* __restrict__ hist, int E, int tile, int NBUCK,
    const float* __restrict__ W1, const float* __restrict__ root1,
    ushort* __restrict__ Bh1, ushort* __restrict__ Bl1,
    const float* __restrict__ W2, const float* __restrict__ root2,
    ushort* __restrict__ Bh2, ushort* __restrict__ Bl2,
    const float* __restrict__ Wd1, ushort* __restrict__ Bd1h) {
  int tid = threadIdx.x;
  if (blockIdx.x >= 256) {
    int e = (blockIdx.x - 256) * 256 + tid;
    if (e < 32768) {
      pack_one<128, 64>(e, W1, root1, Bh1, Bl1);
    } else if (e < 32768 + 8192) {
      pack_one<64, 32>(e - 32768, W2, root2, Bh2, Bl2);
    } else if (e < 32768 + 8192 + 4096) {
      int r = e - 32768 - 8192;          // Wd1: K=64, TN=64, single slab
      int k = r >> 6, n = r & 63;
      int kc = k >> 5, quad = (k >> 3) & 3, j = k & 7, nt = n >> 4, nn = n & 15;
      Bd1h[((kc * 4 + nt) * 64 + quad * 16 + nn) * 8 + j] = f2bf(Wd1[k * 64 + n]);
    }
    return;
  }
  __shared__ int lh[512];
  for (int i = tid; i < 512; i += 256) lh[i] = 0;
  __syncthreads();
  int e0 = blockIdx.x * tile, e1 = min(E, e0 + tile);
  for (int e = e0 + tid; e < e1; e += 256) atomicAdd(&lh[ei[E + e] >> 8], 1);
  __syncthreads();
  for (int i = tid; i < NBUCK; i += 256) hist[i * 256 + blockIdx.x] = lh[i];
}

// parallel scan of each bucket row (256 entries) -> exclusive, + rowsum
__global__ __launch_bounds__(256) void scan_rows_kernel(
    int* __restrict__ hist, int* __restrict__ rowsum) {
  __shared__ int sA[256], sB[256];
  int t = threadIdx.x;
  int* row = hist + blockIdx.x * 256;
  int v = row[t];
  sA[t] = v;
  __syncthreads();
  int* src = sA; int* dst = sB;
  for (int off = 1; off < 256; off <<= 1) {
    int x = src[t];
    if (t >= off) x += src[t - off];
    dst[t] = x;
    __syncthreads();
    int* tmp = src; src = dst; dst = tmp;
  }
  row[t] = src[t] - v;
  if (t == 255) rowsum[blockIdx.x] = src[255];
}

// scan of rowsums -> rowbase; rowbase[NBUCK]=E
__global__ __launch_bounds__(512) void scan_top_kernel(
    const int* __restrict__ rowsum, int* __restrict__ rowbase, int NBUCK, int E) {
  __shared__ int sA[512], sB[512];
  int t = threadIdx.x;
  int v = (t < NBUCK) ? rowsum[t] : 0;
  sA[t] = v;
  __syncthreads();
  int* src = sA; int* dst = sB;
  for (int off = 1; off < 512; off <<= 1) {
    int x = src[t];
    if (t >= off) x += src[t - off];
    dst[t] = x;
    __syncthreads();
    int* tmp = src; src = dst; dst = tmp;
  }
  if (t < NBUCK) rowbase[t] = src[t] - v;
  if (t == 0) rowbase[NBUCK] = E;
}

// scatter edges into coarse buckets (LDS cursors, plain 4B stores)
__global__ __launch_bounds__(256) void part_scatter_kernel(
    const int* __restrict__ ei, const int* __restrict__ et,
    const int* __restrict__ hist, const int* __restrict__ rowbase,
    unsigned* __restrict__ rec, int E, int tile, int NBUCK) {
  __shared__ int ctr[512];
  int tid = threadIdx.x;
  for (int i = tid; i < NBUCK; i += 256)
    ctr[i] = hist[i * 256 + blockIdx.x] + rowbase[i];
  __syncthreads();
  int e0 = blockIdx.x * tile, e1 = min(E, e0 + tile);
  for (int e = e0 + tid; e < e1; e += 256) {
    int s = ei[e];
    int d = ei[E + e];
    int t = et[e];
    int p = atomicAdd(&ctr[d >> 8], 1);
    rec[p] = (unsigned)(s | (t << 20) | ((d & 255) << 22));
  }
}

// one block per 256-dst window: per-(rel,dst) counts, sd, and final dst-grouped
// erec = (H-row index t*N+s, scale=1/max(cnt,1)) — LDS atomics only.
__global__ __launch_bounds__(256) void bucket_build_kernel(
    const unsigned* __restrict__ rec, const int* __restrict__ rowbase,
    int2* __restrict__ sd, int2* __restrict__ erec, int N) {
  __shared__ int c3[768];
  __shared__ int sA[256], sB[256];
  __shared__ int cur[256];
  int tid = threadIdx.x;
  int dstBase = blockIdx.x << 8;
  int bs = rowbase[blockIdx.x], be = rowbase[blockIdx.x + 1];
  for (int i = tid; i < 768; i += 256) c3[i] = 0;
  __syncthreads();
  for (int i = bs + tid; i < be; i += 256) {
    unsigned r = rec[i];
    atomicAdd(&c3[((r >> 20) & 3) * 256 + (r >> 22)], 1);
  }
  __syncthreads();
  int dgv = c3[tid] + c3[256 + tid] + c3[512 + tid];
  sA[tid] = dgv;
  __syncthreads();
  int* src = sA; int* dst = sB;
  for (int off = 1; off < 256; off <<= 1) {
    int x = src[tid];
    if (tid >= off) x += src[tid - off];
    dst[tid] = x;
    __syncthreads();
    int* tmp = src; src = dst; dst = tmp;
  }
  int excl = src[tid] - dgv;
  cur[tid] = bs + excl;
  if (dstBase + tid < N) sd[dstBase + tid] = make_int2(bs + excl, dgv);
  __syncthreads();
  for (int i = bs + tid; i < be; i += 256) {
    unsigned r = rec[i];
    int dloc = r >> 22;
    int t = (r >> 20) & 3;
    int p = atomicAdd(&cur[dloc], 1);
    float sc = 1.0f / (float)max(c3[t * 256 + dloc], 1);
    erec[p] = make_int2(t * N + (int)(r & 0xFFFFF), __float_as_int(sc));
  }
}

// Layer-1 split-bf16 MFMA GEMM. Block = 4 waves x 16 rows = 64 rows.
// H slabs (0-2): Ah*Bh + Al*Bh, bf16 out. z slab (3): + Ah*Bl, fp32 + bias.
template <int K, int TN>
__global__ __launch_bounds__(256, 4) void mfma_gemm_kernel(
    const float* __restrict__ A, const ushort* __restrict__ Bh,
    const ushort* __restrict__ Bl, const float* __restrict__ bias,
    ushort* __restrict__ Hb, float* __restrict__ z, int n) {
  constexpr int KC = K / 32;
  constexpr int NTt = TN / 16;
  constexpr int HALF = K * TN / 8;
  __shared__ int4 bsm[2 * HALF];
  const int tid = threadIdx.x;
  const int w = tid >> 6, lane = tid & 63;
  const int quad = lane >> 4, nn = lane & 15;
  const int rowBase = blockIdx.x * 64 + w * 16;

  int row = rowBase + nn;
  if (row >= n) row = n - 1;  // clamp; stores are guarded
  const float* ap = &A[(size_t)row * K + quad * 8];
  bf16x8 ah[KC], al[KC];
#pragma unroll
  for (int kc = 0; kc < KC; kc++) {
    float4 f0 = *(const float4*)(ap + kc * 32);
    float4 f1 = *(const float4*)(ap + kc * 32 + 4);
    float f[8] = {f0.x, f0.y, f0.z, f0.w, f1.x, f1.y, f1.z, f1.w};
#pragma unroll
    for (int j = 0; j < 8; j++) {
      unsigned short h = f2bf(f[j]);
      ah[kc][j] = (short)h;
      al[kc][j] = (short)f2bf(f[j] - bf2f(h));
    }
  }

  const short* bsp = (const short*)bsm;

#pragma unroll 1
  for (int slab = 0; slab < 4; slab++) {
    __syncthreads();
    {
      const int4* gh = (const int4*)(Bh + (size_t)slab * K * TN);
      for (int i = tid; i < HALF; i += 256) bsm[i] = gh[i];
      if (slab == 3) {
        const int4* gl = (const int4*)(Bl + (size_t)slab * K * TN);
        for (int i = tid; i < HALF; i += 256) bsm[HALF + i] = gl[i];
      }
    }
    __syncthreads();

    f32x4 acc[NTt];
#pragma unroll
    for (int j = 0; j < NTt; j++) acc[j] = (f32x4){0.f, 0.f, 0.f, 0.f};

#pragma unroll
    for (int kc = 0; kc < KC; kc++) {
#pragma unroll
      for (int nt = 0; nt < NTt; nt++) {
        bf16x8 b = *(const bf16x8*)&bsp[((kc * NTt + nt) * 64 + lane) * 8];
        acc[nt] = __builtin_amdgcn_mfma_f32_16x16x32_bf16(ah[kc], b, acc[nt], 0, 0, 0);
        acc[nt] = __builtin_amdgcn_mfma_f32_16x16x32_bf16(al[kc], b, acc[nt], 0, 0, 0);
      }
    }
    if (slab == 3) {
#pragma unroll
      for (int kc = 0; kc < KC; kc++) {
#pragma unroll
        for (int nt = 0; nt < NTt; nt++) {
          bf16x8 b = *(const bf16x8*)&bsp[(HALF * 8) + ((kc * NTt + nt) * 64 + lane) * 8];
          acc[nt] = __builtin_amdgcn_mfma_f32_16x16x32_bf16(ah[kc], b, acc[nt], 0, 0, 0);
        }
      }
    }

    int grow0 = rowBase + quad * 4;
#pragma unroll
    for (int nt = 0; nt < NTt; nt++) {
      int col = nt * 16 + nn;
#pragma unroll
      for (int rg = 0; rg < 4; rg++) {
        int grow = grow0 + rg;
        if (grow < n) {
          float v = acc[nt][rg];
          if (slab == 3) z[(size_t)grow * TN + col] = v + bias[col];
          else Hb[((size_t)slab * n + grow) * TN + col] = f2bf(v);
        }
      }
    }
  }
}

// Layer-2 pure-bf16 MFMA GEMM (A = z1b bf16, no split). K=64, TN=32.
__global__ __launch_bounds__(256, 4) void mfma_gemm2_kernel(
    const ushort* __restrict__ Ab, const ushort* __restrict__ Bh,
    const ushort* __restrict__ Bl, const float* __restrict__ bias,
    ushort* __restrict__ Hb, float* __restrict__ z2r, int n) {
  constexpr int KC = 2, NTt = 2, HALF = 64 * 32 / 8;
  __shared__ int4 bsm[2 * HALF];
  const int tid = threadIdx.x;
  const int w = tid >> 6, lane = tid & 63;
  const int quad = lane >> 4, nn = lane & 15;
  const int rowBase = blockIdx.x * 64 + w * 16;

  int row = rowBase + nn;
  if (row >= n) row = n - 1;
  const ushort* ap = &Ab[(size_t)row * 64 + quad * 8];
  bf16x8 ah[KC];
  ah[0] = *(const bf16x8*)(ap);
  ah[1] = *(const bf16x8*)(ap + 32);

  const short* bsp = (const short*)bsm;

#pragma unroll 1
  for (int slab = 0; slab < 4; slab++) {
    __syncthreads();
    {
      const int4* gh = (const int4*)(Bh + (size_t)slab * 64 * 32);
      for (int i = tid; i < HALF; i += 256) bsm[i] = gh[i];
      if (slab == 3) {
        const int4* gl = (const int4*)(Bl + (size_t)slab * 64 * 32);
        for (int i = tid; i < HALF; i += 256) bsm[HALF + i] = gl[i];
      }
    }
    __syncthreads();

    f32x4 acc[NTt];
#pragma unroll
    for (int j = 0; j < NTt; j++) acc[j] = (f32x4){0.f, 0.f, 0.f, 0.f};

#pragma unroll
    for (int kc = 0; kc < KC; kc++) {
#pragma unroll
      for (int nt = 0; nt < NTt; nt++) {
        bf16x8 b = *(const bf16x8*)&bsp[((kc * NTt + nt) * 64 + lane) * 8];
        acc[nt] = __builtin_amdgcn_mfma_f32_16x16x32_bf16(ah[kc], b, acc[nt], 0, 0, 0);
      }
    }
    if (slab == 3) {
#pragma unroll
      for (int kc = 0; kc < KC; kc++) {
#pragma unroll
        for (int nt = 0; nt < NTt; nt++) {
          bf16x8 b = *(const bf16x8*)&bsp[(HALF * 8) + ((kc * NTt + nt) * 64 + lane) * 8];
          acc[nt] = __builtin_amdgcn_mfma_f32_16x16x32_bf16(ah[kc], b, acc[nt], 0, 0, 0);
        }
      }
    }

    int grow0 = rowBase + quad * 4;
#pragma unroll
    for (int nt = 0; nt < NTt; nt++) {
      int col = nt * 16 + nn;
#pragma unroll
      for (int rg = 0; rg < 4; rg++) {
        int grow = grow0 + rg;
        if (grow < n) {
          float v = acc[nt][rg];
          if (slab == 3) z2r[(size_t)grow * 32 + col] = v + bias[col];
          else Hb[((size_t)slab * n + grow) * 32 + col] = f2bf(v);
        }
      }
    }
  }
}

// ---- pull, C=64: 8 lanes per node (lane owns 8 channels), 8 nodes/wave.
// No cross-lane reduce. erec = (row, scale). Fuses root add + ReLU -> bf16.
__global__ __launch_bounds__(256) void pull64_kernel(
    const ushort* __restrict__ Hb, const int2* __restrict__ erec,
    const int2* __restrict__ sd, const float* __restrict__ z1r,
    ushort* __restrict__ z1b, int N) {
  int w = (blockIdx.x * 256 + threadIdx.x) >> 3;
  if (w >= N) return;
  int q = threadIdx.x & 7;
  int2 s2 = sd[w];
  f32x2 a0 = {0.f, 0.f}, a1 = a0, a2 = a0, a3 = a0;
  for (int i = 0; i < s2.y; i++) {
    int2 r = erec[s2.x + i];
    float sc = __int_as_float(r.y);
    f32x2 sc2 = {sc, sc};
    uint4 v = *(const uint4*)&Hb[(size_t)r.x * 64 + q * 8];
    a0 += bfpair(v.x) * sc2;
    a1 += bfpair(v.y) * sc2;
    a2 += bfpair(v.z) * sc2;
    a3 += bfpair(v.w) * sc2;
  }
  const float4* zr = (const float4*)&z1r[(size_t)w * 64 + q * 8];
  float4 r0 = zr[0], r1 = zr[1];
  uint4 st;
  st.x = pk2(fmaxf(r0.x + a0[0], 0.f), fmaxf(r0.y + a0[1], 0.f));
  st.y = pk2(fmaxf(r0.z + a1[0], 0.f), fmaxf(r0.w + a1[1], 0.f));
  st.z = pk2(fmaxf(r1.x + a2[0], 0.f), fmaxf(r1.y + a2[1], 0.f));
  st.w = pk2(fmaxf(r1.z + a3[0], 0.f), fmaxf(r1.w + a3[1], 0.f));
  *(uint4*)&z1b[(size_t)w * 64 + q * 8] = st;
}

// ---- pull, C=32: 4 lanes per node, 16 nodes/wave. No reduce, no ReLU.
__global__ __launch_bounds__(256) void pull32_kernel(
    const ushort* __restrict__ Hb, const int2* __restrict__ erec,
    const int2* __restrict__ sd, const float* __restrict__ z2r,
    ushort* __restrict__ z2b, int N) {
  int w = (blockIdx.x * 256 + threadIdx.x) >> 2;
  if (w >= N) return;
  int q = threadIdx.x & 3;
  int2 s2 = sd[w];
  f32x2 a0 = {0.f, 0.f}, a1 = a0, a2 = a0, a3 = a0;
  for (int i = 0; i < s2.y; i++) {
    int2 r = erec[s2.x + i];
    float sc = __int_as_float(r.y);
    f32x2 sc2 = {sc, sc};
    uint4 v = *(const uint4*)&Hb[(size_t)r.x * 32 + q * 8];
    a0 += bfpair(v.x) * sc2;
    a1 += bfpair(v.y) * sc2;
    a2 += bfpair(v.z) * sc2;
    a3 += bfpair(v.w) * sc2;
  }
  const float4* zr = (const float4*)&z2r[(size_t)w * 32 + q * 8];
  float4 r0 = zr[0], r1 = zr[1];
  uint4 st;
  st.x = pk2(r0.x + a0[0], r0.y + a0[1]);
  st.y = pk2(r0.z + a1[0], r0.w + a1[1]);
  st.z = pk2(r1.x + a2[0], r1.y + a2[1]);
  st.w = pk2(r1.z + a3[0], r1.w + a3[1]);
  *(uint4*)&z2b[(size_t)w * 32 + q * 8] = st;
}

// MFMA decoder: one wave per 16 pred-edges. ef=[z2b[s],z2b[d]] (K=64) @ Wd1
// (bf16 B-frags, LDS) -> relu -> dot w2. A-frag gathered directly from z2b.
__global__ __launch_bounds__(256) void decoder_kernel(
    const ushort* __restrict__ z2b, const int* __restrict__ pe,
    const ushort* __restrict__ Bd1h, const float* __restrict__ bd1,
    const float* __restrict__ Wd2, const float* __restrict__ bd2,
    float* __restrict__ out, int P) {
  __shared__ int4 wsm[512];  // 4096 bf16 = 8 KB
  __shared__ float b1s[64], w2s[64];
  int tid = threadIdx.x;
  {
    const int4* g = (const int4*)Bd1h;
    for (int i = tid; i < 512; i += 256) wsm[i] = g[i];
    if (tid < 64) { b1s[tid] = bd1[tid]; w2s[tid] = Wd2[tid]; }
  }
  __syncthreads();
  const short* bsp = (const short*)wsm;
  int wv = tid >> 6, lane = tid & 63;
  int quad = lane >> 4, nn = lane & 15;
  int p0 = blockIdx.x * 64 + wv * 16;
  int p = min(p0 + nn, P - 1);  // A-row edge index = lane&15
  int s = pe[p], d = pe[P + p];
  bf16x8 a0 = *(const bf16x8*)&z2b[(size_t)s * 32 + quad * 8];  // k 0..31
  bf16x8 a1 = *(const bf16x8*)&z2b[(size_t)d * 32 + quad * 8];  // k 32..63
  f32x4 acc[4];
#pragma unroll
  for (int nt = 0; nt < 4; nt++) acc[nt] = (f32x4){0.f, 0.f, 0.f, 0.f};
#pragma unroll
  for (int nt = 0; nt < 4; nt++) {
    bf16x8 b0 = *(const bf16x8*)&bsp[((0 * 4 + nt) * 64 + lane) * 8];
    acc[nt] = __builtin_amdgcn_mfma_f32_16x16x32_bf16(a0, b0, acc[nt], 0, 0, 0);
    bf16x8 b1 = *(const bf16x8*)&bsp[((1 * 4 + nt) * 64 + lane) * 8];
    acc[nt] = __builtin_amdgcn_mfma_f32_16x16x32_bf16(a1, b1, acc[nt], 0, 0, 0);
  }
  // D: row(edge)=quad*4+rg, col=nt*16+nn. Per-lane partial over its 4 cols,
  // then reduce across the 16 nn-lanes of this quad.
  float part[4];
#pragma unroll
  for (int rg = 0; rg < 4; rg++) {
    float t = 0.f;
#pragma unroll
    for (int nt = 0; nt < 4; nt++) {
      int col = nt * 16 + nn;
      float h = fmaxf(acc[nt][rg] + b1s[col], 0.f);
      t += h * w2s[col];
    }
    part[rg] = t;
  }
#pragma unroll
  for (int m = 1; m <= 8; m <<= 1)
#pragma unroll
    for (int rg = 0; rg < 4; rg++) part[rg] += __shfl_xor(part[rg], m);
  if (nn == 0) {
    float base = bd2[0];
#pragma unroll
    for (int rg = 0; rg < 4; rg++) {
      int po = p0 + quad * 4 + rg;
      if (po < P) out[po] = part[rg] + base;
    }
  }
}

extern "C" void kernel_launch(void* const* d_in, const int* in_sizes, int n_in,
                              void* d_out, int out_size, void* d_ws, size_t ws_size,
                              hipStream_t stream) {
  const float* x     = (const float*)d_in[0];
  const int*   ei    = (const int*)d_in[1];
  const int*   et    = (const int*)d_in[2];
  const int*   pe    = (const int*)d_in[3];
  const float* W1    = (const float*)d_in[4];
  const float* root1 = (const float*)d_in[5];
  const float* b1    = (const float*)d_in[6];
  const float* W2    = (const float*)d_in[7];
  const float* root2 = (const float*)d_in[8];
  const float* b2    = (const float*)d_in[9];
  const float* Wd1   = (const float*)d_in[10];
  const float* bd1   = (const float*)d_in[11];
  const float* Wd2   = (const float*)d_in[12];
  const float* bd2   = (const float*)d_in[13];
  float* out = (float*)d_out;

  const int N = in_sizes[0] / 128;  // 100000
  const int E = in_sizes[2];        // 1600000
  const int P = in_sizes[3] / 2;    // 200000

  const int NBUCK = (N + 255) >> 8;   // 256-dst windows (<=512)
  const int tile  = (E + 255) / 256;  // edges per partition block

  // Workspace layout (float units; N%4==0 so kN offsets stay 16B-aligned):
  //   z1r:0..64N  z1b(bf16):64N..96N  z2r:96N..128N  z2b(bf16):128N..144N
  //   Hb(bf16):144N..240N  Bpack:240N..241N
  //   ints @241N: sd 2N | erec 2E | rowbase 1024 | rowsum 1024 | hist | rec E
  float* ws   = (float*)d_ws;
  float* z1r  = ws;
  ushort* z1b = (ushort*)(ws + (size_t)64 * N);
  float* z2r  = ws + (size_t)96 * N;
  ushort* z2b = (ushort*)(ws + (size_t)128 * N);
  ushort* Hb  = (ushort*)(ws + (size_t)144 * N);
  ushort* Bh1 = (ushort*)(ws + (size_t)240 * N);  // 32768
  ushort* Bl1 = Bh1 + 32768;                      // 32768
  ushort* Bh2 = Bl1 + 32768;                      // 8192
  ushort* Bl2 = Bh2 + 8192;                       // 8192
  ushort* Bd1h = Bl2 + 8192;                      // 4096
  int* ib      = (int*)(ws + (size_t)241 * N);
  int2* sd     = (int2*)ib;                       // N int2
  int2* erec   = (int2*)(ib + 2 * (size_t)N);     // E int2
  int* rowbase = ib + 2 * (size_t)N + 2 * (size_t)E;  // NBUCK+1 (pad 1024)
  int* rowsum  = rowbase + 1024;                  // pad 1024
  int* hist    = rowsum + 1024;                   // NBUCK*256
  unsigned* rec = (unsigned*)(hist + (size_t)NBUCK * 256);  // E

  // --- CSR build (parallel scans) + all weight packing in dispatch 1 ---
  hist_pack_kernel<<<256 + 176, 256, 0, stream>>>(
      ei, hist, E, tile, NBUCK, W1, root1, Bh1, Bl1, W2, root2, Bh2, Bl2,
      Wd1, Bd1h);
  scan_rows_kernel<<<NBUCK, 256, 0, stream>>>(hist, rowsum);
  scan_top_kernel<<<1, 512, 0, stream>>>(rowsum, rowbase, NBUCK, E);
  part_scatter_kernel<<<256, 256, 0, stream>>>(ei, et, hist, rowbase, rec, E, tile, NBUCK);
  bucket_build_kernel<<<NBUCK, 256, 0, stream>>>(rec, rowbase, sd, erec, N);

  const int gb = (N + 63) / 64;

  // --- layer 1: K=128 -> 64 (fp32 A, split-bf16) ---
  mfma_gemm_kernel<128, 64><<<gb, 256, 0, stream>>>(x, Bh1, Bl1, b1, Hb, z1r, N);
  pull64_kernel<<<((size_t)N * 8 + 255) / 256, 256, 0, stream>>>(Hb, erec, sd, z1r, z1b, N);

  // --- layer 2: K=64 -> 32 (bf16 A, no split) ---
  mfma_gemm2_kernel<<<gb, 256, 0, stream>>>(z1b, Bh2, Bl2, b2, Hb, z2r, N);
  pull32_kernel<<<((size_t)N * 4 + 255) / 256, 256, 0, stream>>>(Hb, erec, sd, z2r, z2b, N);

  // --- decoder (MFMA) ---
  decoder_kernel<<<(P + 63) / 64, 256, 0, stream>>>(z2b, pe, Bd1h, bd1, Wd2, bd2, out, P);
}